// Round 9
// baseline (52.134 us; speedup 1.0000x reference)
//
#include <hip/hip_runtime.h>
#include <math.h>

// ---------------------------------------------------------------------------
// B=32 queries [B,512] fp32 vs N=20000 keys [N,512] fp32.
// scores = Q K^T / sqrt(512); softmax over N; top-8; gather values rows.
// Output = [B*8 weights f32] ++ [B*8 * 10240 values f32].
//
// R9: 2 kernels, no grid sync.
//  K1 score_part: q->bf16 LDS + bf16 MFMA -> scores in LDS -> per-row
//     (m, sum-exp, top-8 of 64) partials. vs R8: FULL K-loop unroll +
//     __launch_bounds__(256,1) so loads hoist deep (R8 était latency-bound
//     at ~2.8 TB/s; need ~5.7MB in flight for 6.3 TB/s).
//  K2 merge_gather: 1024 blocks; each block REDUNDANTLY computes its row's
//     merge of 313 partials -> top-12 -> EXACT fp32 rescore (deterministic,
//     L2-hot) -> own rank's index in LDS -> gathers its quarter segment.
//     Kills the K2->K3 edge (~5us) and the tidx global round-trip.
// ---------------------------------------------------------------------------

#define TOPK 8
#define DKD 512
#define NEG  -1.0e30f

typedef __attribute__((ext_vector_type(8))) short short8;
typedef __attribute__((ext_vector_type(4))) float f32x4;

__device__ inline unsigned short f2bf(float x) {
    unsigned int u = __float_as_uint(x);
    u = (u + 0x7fffu + ((u >> 16) & 1u)) >> 16;   // RNE to bf16
    return (unsigned short)u;
}

// comparator everywhere: value desc, index asc (matches lax.top_k ties)
__device__ inline void wave_argmax(float& v, int& i) {
    #pragma unroll
    for (int off = 1; off < 64; off <<= 1) {
        float ov = __shfl_xor(v, off);
        int   oi = __shfl_xor(i, off);
        if (ov > v || (ov == v && oi < i)) { v = ov; i = oi; }
    }
}

// sorted-desc top-8 insert (boolean network, strict > keeps earlier index on ties)
__device__ inline void top8_insert(float (&v)[8], int (&ji)[8], float x, int gi) {
    if (x > v[7]) {
        bool g[8];
        #pragma unroll
        for (int k = 0; k < 8; ++k) g[k] = (x > v[k]);
        #pragma unroll
        for (int k = 7; k >= 1; --k) {
            v[k]  = g[k] ? (g[k - 1] ? v[k - 1] : x)  : v[k];
            ji[k] = g[k] ? (g[k - 1] ? ji[k - 1] : gi) : ji[k];
        }
        v[0]  = g[0] ? x  : v[0];
        ji[0] = g[0] ? gi : ji[0];
    }
}

// ---- K1: MFMA scores (64 keys/block) + in-block per-row partials ----------
__global__ __launch_bounds__(256, 1) void score_part_kernel(
    const float* __restrict__ q, const float* __restrict__ keys,
    float* __restrict__ pmg, float* __restrict__ psg,
    float* __restrict__ cvg, int* __restrict__ cig, int N, int NTB)
{
    const int tid  = threadIdx.x;
    const int lane = tid & 63;
    const int wid  = tid >> 6;
    const float scale = 0.04419417382415922f;   // 1/sqrt(512)

    __shared__ short qs[32][DKD + 8];   // bf16 q, +8 pad (2-way banks = free)
    __shared__ float S[32][65];         // scores tile, +1 pad

    // ---- P0: q -> bf16 into LDS (64KB read, 1x per block) ----
    #pragma unroll
    for (int i = 0; i < 16; ++i) {
        const int idx = i * 256 + tid;          // 0..4095 float4s
        const int row = idx >> 7;               // 128 float4 per row
        const int c4  = idx & 127;
        float4 v = *reinterpret_cast<const float4*>(&q[row * DKD + c4 * 4]);
        ushort4 h;
        h.x = f2bf(v.x); h.y = f2bf(v.y); h.z = f2bf(v.z); h.w = f2bf(v.w);
        *reinterpret_cast<ushort4*>(&qs[row][c4 * 4]) = h;
    }
    __syncthreads();

    // ---- P1: 16-key MFMA tile per wave, FULL unroll for deep load hoisting -
    {
        const int col = lane & 15;
        const int kg  = lane >> 4;
        const int n0  = blockIdx.x * 64 + wid * 16;

        f32x4 acc0 = {0.f, 0.f, 0.f, 0.f};
        f32x4 acc1 = {0.f, 0.f, 0.f, 0.f};

        int nrow = n0 + col;
        const bool valid = (nrow < N);
        if (!valid) nrow = N - 1;               // clamp loads
        const float* krow = keys + (size_t)nrow * DKD + kg * 8;
        const short* s0 = &qs[col][kg * 8];
        const short* s1 = &qs[col + 16][kg * 8];

        #pragma unroll
        for (int ks = 0; ks < 16; ++ks) {
            const int d = ks * 32;
            float4 ka = *reinterpret_cast<const float4*>(krow + d);
            float4 kb = *reinterpret_cast<const float4*>(krow + d + 4);
            short8 fh;
            fh[0] = (short)f2bf(ka.x); fh[1] = (short)f2bf(ka.y);
            fh[2] = (short)f2bf(ka.z); fh[3] = (short)f2bf(ka.w);
            fh[4] = (short)f2bf(kb.x); fh[5] = (short)f2bf(kb.y);
            fh[6] = (short)f2bf(kb.z); fh[7] = (short)f2bf(kb.w);
            short8 a0 = *reinterpret_cast<const short8*>(s0 + d);
            short8 a1 = *reinterpret_cast<const short8*>(s1 + d);
            acc0 = __builtin_amdgcn_mfma_f32_16x16x32_bf16(a0, fh, acc0, 0, 0, 0);
            acc1 = __builtin_amdgcn_mfma_f32_16x16x32_bf16(a1, fh, acc1, 0, 0, 0);
        }

        // D layout (m89-verified): col = lane&15, row = (lane>>4)*4 + reg
        #pragma unroll
        for (int j = 0; j < 4; ++j) {
            const int r = kg * 4 + j;
            S[r][wid * 16 + col]      = valid ? acc0[j] * scale : NEG;
            S[r + 16][wid * 16 + col] = valid ? acc1[j] * scale : NEG;
        }
    }
    __syncthreads();

    // ---- P2: per-row partials: 8 threads/row x 8 cols each ----
    {
        const int r = tid >> 3;                 // row 0..31
        const int g = tid & 7;                  // 8-lane group position
        float m = NEG, s = 0.f;
        float v[8]; int ji[8];
        #pragma unroll
        for (int k = 0; k < 8; ++k) { v[k] = NEG; ji[k] = 0x7ffffffe; }

        #pragma unroll
        for (int e = 0; e < 8; ++e) {
            const int c  = g * 8 + e;
            const float x = S[r][c];
            const int  gi = blockIdx.x * 64 + c;
            if (x > -5e29f) {                   // skip invalid-key sentinels
                const float nm = fmaxf(m, x);
                s = s * __expf(m - nm) + __expf(x - nm);
                m = nm;
                top8_insert(v, ji, x, gi);
            }
        }

        // group (m,s) combine over 8 lanes
        #pragma unroll
        for (int off = 1; off < 8; off <<= 1) {
            float om = __shfl_xor(m, off), os = __shfl_xor(s, off);
            float M2 = fmaxf(m, om);
            s = s * __expf(m - M2) + os * __expf(om - M2);
            m = M2;
        }

        // group top-8 selection (8 rounds over 8 sorted lists)
        float sel_v[8]; int sel_i[8];
        #pragma unroll
        for (int rr = 0; rr < 8; ++rr) {
            float mv = v[0]; int mi = ji[0];
            #pragma unroll
            for (int off = 1; off < 8; off <<= 1) {
                float ov = __shfl_xor(mv, off);
                int   oi = __shfl_xor(mi, off);
                if (ov > mv || (ov == mv && oi < mi)) { mv = ov; mi = oi; }
            }
            if (v[0] == mv && ji[0] == mi) {    // I won: pop my head
                #pragma unroll
                for (int k = 0; k < 7; ++k) { v[k] = v[k + 1]; ji[k] = ji[k + 1]; }
                v[7] = NEG; ji[7] = 0x7ffffffe;
            }
            sel_v[rr] = mv; sel_i[rr] = mi;
        }

        if (g == 0) {
            const size_t base = (size_t)r * NTB + blockIdx.x;
            pmg[base] = m; psg[base] = s;
            #pragma unroll
            for (int k = 0; k < 8; ++k) {
                cvg[base * 8 + k] = sel_v[k];
                cig[base * 8 + k] = sel_i[k];
            }
        }
    }
}

// ---- K2: per (out-row, quarter): redundant row merge -> own idx -> gather -
__global__ __launch_bounds__(256) void merge_gather_kernel(
    const float* __restrict__ pmg, const float* __restrict__ psg,
    const float* __restrict__ cvg, const int* __restrict__ cig,
    const float* __restrict__ q, const float* __restrict__ keys,
    const float* __restrict__ values,
    float* __restrict__ out_w, float* __restrict__ out_v, int NTB, int LDV)
{
    const int bk   = blockIdx.x >> 2;           // output row 0..255
    const int qtr  = blockIdx.x & 3;
    const int b    = bk >> 3;                   // query row
    const int krk  = bk & 7;                    // rank within top-8
    const int tid  = threadIdx.x;
    const int lane = tid & 63;
    const int wid  = tid >> 6;
    const float scale = 0.04419417382415922f;

    __shared__ float lm[4], ls[4], lcv[4][TOPK];
    __shared__ int   lci[4][TOPK];
    __shared__ int   s_id;

    // ---- thread-local: combine ~2 tiles' partials ----
    float m = NEG, s = 0.f;
    float v[8]; int ji[8];
    #pragma unroll
    for (int k = 0; k < 8; ++k) { v[k] = NEG; ji[k] = 0x7ffffffe; }

    for (int tb = tid; tb < NTB; tb += 256) {
        const size_t base = (size_t)b * NTB + tb;
        const float pm_t = pmg[base], ps_t = psg[base];
        const float M2 = fmaxf(m, pm_t);
        s = s * __expf(m - M2) + ps_t * __expf(pm_t - M2);
        m = M2;
        #pragma unroll
        for (int k = 0; k < 8; ++k) {
            top8_insert(v, ji, cvg[base * 8 + k], cig[base * 8 + k]);
        }
    }

    // ---- wave-level (m,s) combine ----
    #pragma unroll
    for (int off = 1; off < 64; off <<= 1) {
        float om = __shfl_xor(m, off), os = __shfl_xor(s, off);
        float M2 = fmaxf(m, om);
        s = s * __expf(m - M2) + os * __expf(om - M2);
        m = M2;
    }

    // ---- wave-level top-8 merge: 8 selection rounds ----
    float selv = 0.f; int seli = 0;
    #pragma unroll
    for (int r = 0; r < TOPK; ++r) {
        float mv = v[0]; int mi = ji[0];
        wave_argmax(mv, mi);
        if (v[0] == mv && ji[0] == mi) {       // I won: pop my head
            #pragma unroll
            for (int k = 0; k < TOPK - 1; ++k) { v[k] = v[k + 1]; ji[k] = ji[k + 1]; }
            v[TOPK - 1] = NEG; ji[TOPK - 1] = 0x7ffffffe;
        }
        if (lane == r) { selv = mv; seli = mi; }
    }

    if (lane == 0) { lm[wid] = m; ls[wid] = s; }
    if (lane < TOPK) { lcv[wid][lane] = selv; lci[wid][lane] = seli; }
    __syncthreads();

    if (wid == 0) {
        // ---- cross-wave combine (all lanes of wave 0 redundantly) ----
        float M = lm[0], S = ls[0];
        #pragma unroll
        for (int cc = 1; cc < 4; ++cc) {
            float M2 = fmaxf(M, lm[cc]);
            S = S * __expf(M - M2) + ls[cc] * __expf(lm[cc] - M2);
            M = M2;
        }

        // ---- 32 candidates -> approx top-12 ----
        float vv = (lane < 32) ? lcv[lane >> 3][lane & 7] : NEG;
        int   ii = (lane < 32) ? lci[lane >> 3][lane & 7] : 0x7ffffffe;
        int   si = 0x7ffffffe;
        #pragma unroll
        for (int r = 0; r < 12; ++r) {
            float mv = vv; int mi = ii;
            wave_argmax(mv, mi);
            if (vv == mv && ii == mi) vv = NEG;
            if (lane == r) si = mi;
        }

        // ---- exact fp32 rescore of the 12 candidates ----
        float4 qa = *reinterpret_cast<const float4*>(q + (size_t)b * DKD + lane * 8);
        float4 qb = *reinterpret_cast<const float4*>(q + (size_t)b * DKD + lane * 8 + 4);
        float exv = NEG;
        #pragma unroll
        for (int r = 0; r < 12; ++r) {
            const int cand = __shfl(si, r);
            const float* kr = keys + (size_t)cand * DKD + lane * 8;
            float4 k1 = *reinterpret_cast<const float4*>(kr);
            float4 k2 = *reinterpret_cast<const float4*>(kr + 4);
            float p = qa.x * k1.x + qa.y * k1.y + qa.z * k1.z + qa.w * k1.w
                    + qb.x * k2.x + qb.y * k2.y + qb.z * k2.z + qb.w * k2.w;
            #pragma unroll
            for (int off = 1; off < 64; off <<= 1) p += __shfl_xor(p, off);
            if (lane == r) exv = p * scale;
        }

        // ---- exact top-8 of 12; stash own rank's index; maybe weights ----
        float fv = (lane < 12) ? exv : NEG;
        int   fi = (lane < 12) ? si : 0x7ffffffe;
        #pragma unroll
        for (int r = 0; r < TOPK; ++r) {
            float mv = fv; int mi = fi;
            wave_argmax(mv, mi);
            if (fv == mv && fi == mi) fv = NEG;
            if (lane == r) {
                if (r == krk) s_id = mi;
                if (qtr == 0 && krk == 0)
                    out_w[b * TOPK + r] = __expf(mv - M) / S;
            }
        }
    }
    __syncthreads();

    // ---- gather this (row, quarter) segment ----
    const int id = s_id;
    const float4* src = reinterpret_cast<const float4*>(values + (size_t)id * LDV);
    float4*       dst = reinterpret_cast<float4*>(out_v + (size_t)bk * LDV);
    const int n4 = LDV >> 2;                 // 2560
    const int qn = n4 >> 2;                  // 640
    for (int i = qtr * qn + tid; i < (qtr + 1) * qn; i += 256)
        dst[i] = src[i];
}

extern "C" void kernel_launch(void* const* d_in, const int* in_sizes, int n_in,
                              void* d_out, int out_size, void* d_ws, size_t ws_size,
                              hipStream_t stream) {
    const float* q      = (const float*)d_in[0];
    const float* keys   = (const float*)d_in[1];
    const float* values = (const float*)d_in[2];

    const int B   = in_sizes[0] / DKD;                 // 32
    const int N   = in_sizes[1] / DKD;                 // 20000
    const int LDV = (int)((long long)in_sizes[2] / N); // 10240
    const int NTB = (N + 63) / 64;                     // 313

    float* out   = (float*)d_out;
    float* out_w = out;
    float* out_v = out + (size_t)B * TOPK;

    char* wsb = (char*)d_ws;
    size_t off = 0;
    float* pmg = (float*)(wsb + off); off += (size_t)B * NTB * sizeof(float);
    float* psg = (float*)(wsb + off); off += (size_t)B * NTB * sizeof(float);
    float* cvg = (float*)(wsb + off); off += (size_t)B * NTB * 8 * sizeof(float);
    int*   cig = (int*)(wsb + off);   off += (size_t)B * NTB * 8 * sizeof(int);

    score_part_kernel<<<NTB, 256, 0, stream>>>(q, keys, pmg, psg, cvg, cig, N, NTB);
    merge_gather_kernel<<<B * TOPK * 4, 256, 0, stream>>>(
        pmg, psg, cvg, cig, q, keys, values, out_w, out_v, NTB, LDV);
}

// Round 10
// 49.120 us; speedup vs baseline: 1.0614x; 1.0614x over previous
//
#include <hip/hip_runtime.h>
#include <math.h>

// ---------------------------------------------------------------------------
// B=32 queries [B,512] fp32 vs N=20000 keys [N,512] fp32.
// scores = Q K^T / sqrt(512); softmax over N; top-8; gather values rows.
// Output = [B*8 weights f32] ++ [B*8 * 10240 values f32].
//
// R10: 3 kernels. K1 rebuilt for OCCUPANCY (R8/R9 evidence: K1 was
// latency-bound at 4.9 waves/CU because keys/wave=16 pinned wave count).
//  K1 score_part: 625 blocks x 512 thr = 8 waves: 2 key-subtiles x 4
//     K-quarters (K=128/wave). 5000 waves -> 19.5/CU. Q-frags preloaded to
//     registers (LDS out of hot loop); qs pad +2 (stride%32==1, ~conflict-
//     free); K-quarter partials summed deterministically via LDS Sp.
//     Per-row (m, sum-exp, top-8 of 32) partials out.
//  K2 row_merge: per row: merge 625 partials -> top-12 -> EXACT fp32
//     rescore -> weights + indices (R8-proven).
//  K3 gather: values[idx] rows, 4 blocks/row (R8-proven).
// ---------------------------------------------------------------------------

#define TOPK 8
#define DKD 512
#define NEG  -1.0e30f

typedef __attribute__((ext_vector_type(8))) short short8;
typedef __attribute__((ext_vector_type(4))) float f32x4;

__device__ inline unsigned short f2bf(float x) {
    unsigned int u = __float_as_uint(x);
    u = (u + 0x7fffu + ((u >> 16) & 1u)) >> 16;   // RNE to bf16
    return (unsigned short)u;
}

// comparator everywhere: value desc, index asc (matches lax.top_k ties)
__device__ inline void wave_argmax(float& v, int& i) {
    #pragma unroll
    for (int off = 1; off < 64; off <<= 1) {
        float ov = __shfl_xor(v, off);
        int   oi = __shfl_xor(i, off);
        if (ov > v || (ov == v && oi < i)) { v = ov; i = oi; }
    }
}

// sorted-desc top-8 insert (boolean network, strict > keeps earlier index on ties)
__device__ inline void top8_insert(float (&v)[8], int (&ji)[8], float x, int gi) {
    if (x > v[7]) {
        bool g[8];
        #pragma unroll
        for (int k = 0; k < 8; ++k) g[k] = (x > v[k]);
        #pragma unroll
        for (int k = 7; k >= 1; --k) {
            v[k]  = g[k] ? (g[k - 1] ? v[k - 1] : x)  : v[k];
            ji[k] = g[k] ? (g[k - 1] ? ji[k - 1] : gi) : ji[k];
        }
        v[0]  = g[0] ? x  : v[0];
        ji[0] = g[0] ? gi : ji[0];
    }
}

// ---- K1: K-split MFMA scores (32 keys/block, 8 waves) + per-row partials --
__global__ __launch_bounds__(512) void score_part_kernel(
    const float* __restrict__ q, const float* __restrict__ keys,
    float* __restrict__ pmg, float* __restrict__ psg,
    float* __restrict__ cvg, int* __restrict__ cig, int N, int NTB)
{
    const int tid  = threadIdx.x;
    const int lane = tid & 63;
    const int wid  = tid >> 6;                  // 8 waves
    const float scale = 0.04419417382415922f;   // 1/sqrt(512)

    __shared__ short qs[32][DKD + 2];   // +2 pad: stride 514*2B = 257 dw ≡ 1 (mod 32)
    __shared__ float Sp[4][32][33];     // per-K-quarter partial scores

    // ---- P0: q -> bf16 into LDS (4096 float4 / 512 thr = 8 each) ----
    #pragma unroll
    for (int i = 0; i < 8; ++i) {
        const int idx = i * 512 + tid;          // 0..4095 float4s
        const int row = idx >> 7;               // 128 float4 per row
        const int c4  = idx & 127;
        float4 v = *reinterpret_cast<const float4*>(&q[row * DKD + c4 * 4]);
        ushort4 h;
        h.x = f2bf(v.x); h.y = f2bf(v.y); h.z = f2bf(v.z); h.w = f2bf(v.w);
        *reinterpret_cast<ushort4*>(&qs[row][c4 * 4]) = h;
    }
    __syncthreads();

    // ---- P1: wave = (key-subtile, K-quarter); 4 MFMA steps over K=128 ----
    {
        const int sub = wid & 1;                // key subtile 0..1
        const int kq  = wid >> 1;               // K quarter 0..3
        const int col = lane & 15;
        const int kg  = lane >> 4;
        const int n0  = blockIdx.x * 32 + sub * 16;

        int nrow = n0 + col;
        if (nrow >= N) nrow = N - 1;            // never triggers (N%32==0), safety
        const float* krow = keys + (size_t)nrow * DKD + kq * 128 + kg * 8;
        const short* s0 = &qs[col][kq * 128 + kg * 8];
        const short* s1 = &qs[col + 16][kq * 128 + kg * 8];

        // preload q fragments to registers: LDS leaves the hot loop
        short8 a0[4], a1[4];
        #pragma unroll
        for (int ks = 0; ks < 4; ++ks) {
            a0[ks] = *reinterpret_cast<const short8*>(s0 + ks * 32);
            a1[ks] = *reinterpret_cast<const short8*>(s1 + ks * 32);
        }

        f32x4 acc0 = {0.f, 0.f, 0.f, 0.f};
        f32x4 acc1 = {0.f, 0.f, 0.f, 0.f};

        #pragma unroll
        for (int ks = 0; ks < 4; ++ks) {
            const int d = ks * 32;
            float4 ka = *reinterpret_cast<const float4*>(krow + d);
            float4 kb = *reinterpret_cast<const float4*>(krow + d + 4);
            short8 fh;
            fh[0] = (short)f2bf(ka.x); fh[1] = (short)f2bf(ka.y);
            fh[2] = (short)f2bf(ka.z); fh[3] = (short)f2bf(ka.w);
            fh[4] = (short)f2bf(kb.x); fh[5] = (short)f2bf(kb.y);
            fh[6] = (short)f2bf(kb.z); fh[7] = (short)f2bf(kb.w);
            acc0 = __builtin_amdgcn_mfma_f32_16x16x32_bf16(a0[ks], fh, acc0, 0, 0, 0);
            acc1 = __builtin_amdgcn_mfma_f32_16x16x32_bf16(a1[ks], fh, acc1, 0, 0, 0);
        }

        // D layout (m89-verified): col = lane&15, row = (lane>>4)*4 + reg
        #pragma unroll
        for (int j = 0; j < 4; ++j) {
            const int r = kg * 4 + j;
            Sp[kq][r][sub * 16 + col]      = acc0[j];
            Sp[kq][r + 16][sub * 16 + col] = acc1[j];
        }
    }
    __syncthreads();

    // ---- P2: per-row partials (threads 0..255): 8 thr/row x 4 cols each ----
    if (tid < 256) {
        const int r = tid >> 3;                 // row 0..31
        const int g = tid & 7;                  // 8-lane group position
        float m = NEG, s = 0.f;
        float v[8]; int ji[8];
        #pragma unroll
        for (int k = 0; k < 8; ++k) { v[k] = NEG; ji[k] = 0x7ffffffe; }

        #pragma unroll
        for (int e = 0; e < 4; ++e) {
            const int c = g * 4 + e;
            const float x = (Sp[0][r][c] + Sp[1][r][c] + Sp[2][r][c] + Sp[3][r][c]) * scale;
            const int gi = blockIdx.x * 32 + c;
            const float nm = fmaxf(m, x);
            s = s * __expf(m - nm) + __expf(x - nm);
            m = nm;
            top8_insert(v, ji, x, gi);
        }

        // group (m,s) combine over 8 lanes
        #pragma unroll
        for (int off = 1; off < 8; off <<= 1) {
            float om = __shfl_xor(m, off), os = __shfl_xor(s, off);
            float M2 = fmaxf(m, om);
            s = s * __expf(m - M2) + os * __expf(om - M2);
            m = M2;
        }

        // group top-8 selection (8 rounds over 8 sorted lists)
        float sel_v[8]; int sel_i[8];
        #pragma unroll
        for (int rr = 0; rr < 8; ++rr) {
            float mv = v[0]; int mi = ji[0];
            #pragma unroll
            for (int off = 1; off < 8; off <<= 1) {
                float ov = __shfl_xor(mv, off);
                int   oi = __shfl_xor(mi, off);
                if (ov > mv || (ov == mv && oi < mi)) { mv = ov; mi = oi; }
            }
            if (v[0] == mv && ji[0] == mi) {    // I won: pop my head
                #pragma unroll
                for (int k = 0; k < 7; ++k) { v[k] = v[k + 1]; ji[k] = ji[k + 1]; }
                v[7] = NEG; ji[7] = 0x7ffffffe;
            }
            sel_v[rr] = mv; sel_i[rr] = mi;
        }

        if (g == 0) {
            const size_t base = (size_t)r * NTB + blockIdx.x;
            pmg[base] = m; psg[base] = s;
            #pragma unroll
            for (int k = 0; k < 8; ++k) {
                cvg[base * 8 + k] = sel_v[k];
                cig[base * 8 + k] = sel_i[k];
            }
        }
    }
}

// ---- K2: per row: merge NTB partials -> top-12 -> exact rescore -----------
__global__ __launch_bounds__(256) void row_merge_kernel(
    const float* __restrict__ pmg, const float* __restrict__ psg,
    const float* __restrict__ cvg, const int* __restrict__ cig,
    const float* __restrict__ q, const float* __restrict__ keys,
    float* __restrict__ out_w, int* __restrict__ tidx, int NTB)
{
    const int b    = blockIdx.x;
    const int tid  = threadIdx.x;
    const int lane = tid & 63;
    const int wid  = tid >> 6;
    const float scale = 0.04419417382415922f;

    __shared__ float lm[4], ls[4], lcv[4][TOPK];
    __shared__ int   lci[4][TOPK];

    // ---- thread-local: combine ~3 tiles' partials ----
    float m = NEG, s = 0.f;
    float v[8]; int ji[8];
    #pragma unroll
    for (int k = 0; k < 8; ++k) { v[k] = NEG; ji[k] = 0x7ffffffe; }

    for (int tb = tid; tb < NTB; tb += 256) {
        const size_t base = (size_t)b * NTB + tb;
        const float pm_t = pmg[base], ps_t = psg[base];
        const float M2 = fmaxf(m, pm_t);
        s = s * __expf(m - M2) + ps_t * __expf(pm_t - M2);
        m = M2;
        #pragma unroll
        for (int k = 0; k < 8; ++k) {
            top8_insert(v, ji, cvg[base * 8 + k], cig[base * 8 + k]);
        }
    }

    // ---- wave-level (m,s) combine ----
    #pragma unroll
    for (int off = 1; off < 64; off <<= 1) {
        float om = __shfl_xor(m, off), os = __shfl_xor(s, off);
        float M2 = fmaxf(m, om);
        s = s * __expf(m - M2) + os * __expf(om - M2);
        m = M2;
    }

    // ---- wave-level top-8 merge: 8 selection rounds ----
    float selv = 0.f; int seli = 0;
    #pragma unroll
    for (int r = 0; r < TOPK; ++r) {
        float mv = v[0]; int mi = ji[0];
        wave_argmax(mv, mi);
        if (v[0] == mv && ji[0] == mi) {       // I won: pop my head
            #pragma unroll
            for (int k = 0; k < TOPK - 1; ++k) { v[k] = v[k + 1]; ji[k] = ji[k + 1]; }
            v[TOPK - 1] = NEG; ji[TOPK - 1] = 0x7ffffffe;
        }
        if (lane == r) { selv = mv; seli = mi; }
    }

    if (lane == 0) { lm[wid] = m; ls[wid] = s; }
    if (lane < TOPK) { lcv[wid][lane] = selv; lci[wid][lane] = seli; }
    __syncthreads();

    if (wid != 0) return;

    // ---- cross-wave combine (all lanes of wave 0 redundantly) ----
    float M = lm[0], S = ls[0];
    #pragma unroll
    for (int cc = 1; cc < 4; ++cc) {
        float M2 = fmaxf(M, lm[cc]);
        S = S * __expf(M - M2) + ls[cc] * __expf(lm[cc] - M2);
        M = M2;
    }

    // ---- 32 candidates -> approx top-12 ----
    float vv = (lane < 32) ? lcv[lane >> 3][lane & 7] : NEG;
    int   ii = (lane < 32) ? lci[lane >> 3][lane & 7] : 0x7ffffffe;
    int   si = 0x7ffffffe;
    #pragma unroll
    for (int r = 0; r < 12; ++r) {
        float mv = vv; int mi = ii;
        wave_argmax(mv, mi);
        if (vv == mv && ii == mi) vv = NEG;
        if (lane == r) si = mi;
    }

    // ---- exact fp32 rescore of the 12 candidates ----
    float4 qa = *reinterpret_cast<const float4*>(q + (size_t)b * DKD + lane * 8);
    float4 qb = *reinterpret_cast<const float4*>(q + (size_t)b * DKD + lane * 8 + 4);
    float exv = NEG;
    #pragma unroll
    for (int r = 0; r < 12; ++r) {
        const int cand = __shfl(si, r);
        const float* kr = keys + (size_t)cand * DKD + lane * 8;
        float4 k1 = *reinterpret_cast<const float4*>(kr);
        float4 k2 = *reinterpret_cast<const float4*>(kr + 4);
        float p = qa.x * k1.x + qa.y * k1.y + qa.z * k1.z + qa.w * k1.w
                + qb.x * k2.x + qb.y * k2.y + qb.z * k2.z + qb.w * k2.w;
        #pragma unroll
        for (int off = 1; off < 64; off <<= 1) p += __shfl_xor(p, off);
        if (lane == r) exv = p * scale;
    }

    // ---- exact top-8 of 12, emit weights (max M cancels num/denom) ----
    float fv = (lane < 12) ? exv : NEG;
    int   fi = (lane < 12) ? si : 0x7ffffffe;
    #pragma unroll
    for (int r = 0; r < TOPK; ++r) {
        float mv = fv; int mi = fi;
        wave_argmax(mv, mi);
        if (fv == mv && fi == mi) fv = NEG;
        if (lane == r) {
            out_w[b * TOPK + r] = __expf(mv - M) / S;
            tidx[b * TOPK + r]  = mi;
        }
    }
}

// ---- K3: gather values rows (4 blocks per output row) ---------------------
__global__ __launch_bounds__(256) void gather_kernel(
    const float* __restrict__ values, const int* __restrict__ idx,
    float* __restrict__ out, int LDV)
{
    const int bk  = blockIdx.x >> 2;
    const int qtr = blockIdx.x & 3;
    const int id = idx[bk];
    const float4* src = reinterpret_cast<const float4*>(values + (size_t)id * LDV);
    float4*       dst = reinterpret_cast<float4*>(out + (size_t)bk * LDV);
    const int n4 = LDV >> 2;                 // 2560
    const int qn = n4 >> 2;                  // 640
    for (int i = qtr * qn + threadIdx.x; i < (qtr + 1) * qn; i += 256)
        dst[i] = src[i];
}

extern "C" void kernel_launch(void* const* d_in, const int* in_sizes, int n_in,
                              void* d_out, int out_size, void* d_ws, size_t ws_size,
                              hipStream_t stream) {
    const float* q      = (const float*)d_in[0];
    const float* keys   = (const float*)d_in[1];
    const float* values = (const float*)d_in[2];

    const int B   = in_sizes[0] / DKD;                 // 32
    const int N   = in_sizes[1] / DKD;                 // 20000
    const int LDV = (int)((long long)in_sizes[2] / N); // 10240
    const int NTB = (N + 31) / 32;                     // 625

    float* out   = (float*)d_out;
    float* out_w = out;
    float* out_v = out + (size_t)B * TOPK;

    char* wsb = (char*)d_ws;
    size_t off = 0;
    float* pmg = (float*)(wsb + off); off += (size_t)B * NTB * sizeof(float);
    float* psg = (float*)(wsb + off); off += (size_t)B * NTB * sizeof(float);
    float* cvg = (float*)(wsb + off); off += (size_t)B * NTB * 8 * sizeof(float);
    int*   cig = (int*)(wsb + off);   off += (size_t)B * NTB * 8 * sizeof(int);
    int*   tidx = (int*)(wsb + off);  off += (size_t)B * TOPK * sizeof(int);

    score_part_kernel<<<NTB, 512, 0, stream>>>(q, keys, pmg, psg, cvg, cig, N, NTB);
    row_merge_kernel<<<B, 256, 0, stream>>>(pmg, psg, cvg, cig, q, keys, out_w, tidx, NTB);
    gather_kernel<<<B * TOPK * 4, 256, 0, stream>>>(values, tidx, out_v, LDV);
}